// Round 3
// baseline (377.095 us; speedup 1.0000x reference)
//
#include <hip/hip_runtime.h>

// WeightedAggregator: out[n,:] = sum_e-in-seg(n) eff_w[e]*feat[nidx[e],:] / den[n]
//   wsum[n] = sum of edge_weights in segment n (segment_ids sorted!)
//   use_mean = (wsum == 0)  -> eff_w = 1, den = deg; else eff_w = w, den = wsum
//   den == 0 -> 1 (empty nodes output zeros)
//
// Strategy: one 64-lane wave per node (D=64, one lane per feature dim).
// Segment range found via binary search on the sorted segment_ids -> no
// atomics, no workspace. Feature row gather is a coalesced 256B load.

#define D_FEAT 64

__device__ __forceinline__ int lower_bound_i32(const int* __restrict__ a, int n, int key) {
    int lo = 0, hi = n;
    while (lo < hi) {
        int mid = (lo + hi) >> 1;
        if (a[mid] < key) lo = mid + 1; else hi = mid;
    }
    return lo;
}

__global__ __launch_bounds__(256) void WeightedAggregator_28424093564968_kernel(
        const float* __restrict__ feat,   // [N, 64]
        const float* __restrict__ ew,     // [E]
        const int*   __restrict__ nidx,   // [E]
        const int*   __restrict__ seg,    // [E] sorted
        float*       __restrict__ out,    // [N, 64]
        int N, int E) {
    const int wave = (blockIdx.x * blockDim.x + threadIdx.x) >> 6;
    const int lane = threadIdx.x & 63;
    if (wave >= N) return;
    const int n = wave;

    // Wave-uniform binary searches (all lanes same address -> broadcast loads).
    const int start = lower_bound_i32(seg, E, n);
    const int end   = lower_bound_i32(seg, E, n + 1);

    // Per-segment weight sum (lanes stride the edge range, coalesced).
    float ws = 0.0f;
    for (int e = start + lane; e < end; e += 64) ws += ew[e];
    #pragma unroll
    for (int off = 32; off > 0; off >>= 1) ws += __shfl_xor(ws, off);

    const bool  use_mean = (ws == 0.0f);
    const float deg = (float)(end - start);
    float den = use_mean ? deg : ws;
    if (den == 0.0f) den = 1.0f;

    // Weighted feature accumulation: per edge, lane-uniform w/idx loads
    // (HW broadcast), then a coalesced 256B feature-row gather.
    float acc = 0.0f;
    for (int e = start; e < end; ++e) {
        const float w   = ew[e];
        const int   idx = nidx[e];
        const float v   = feat[(size_t)idx * D_FEAT + lane];
        acc += (use_mean ? 1.0f : w) * v;
    }

    out[(size_t)n * D_FEAT + lane] = acc / den;
}

extern "C" void kernel_launch(void* const* d_in, const int* in_sizes, int n_in,
                              void* d_out, int out_size, void* d_ws, size_t ws_size,
                              hipStream_t stream) {
    const float* feat = (const float*)d_in[0];
    const float* ew   = (const float*)d_in[1];
    const int*   nidx = (const int*)d_in[2];
    const int*   seg  = (const int*)d_in[3];
    float*       out  = (float*)d_out;

    const int E = in_sizes[1];
    const int N = in_sizes[0] / D_FEAT;

    // One wave (64 lanes) per node, 4 waves per 256-thread block.
    const int waves_per_block = 256 / 64;
    const int grid = (N + waves_per_block - 1) / waves_per_block;
    WeightedAggregator_28424093564968_kernel<<<grid, 256, 0, stream>>>(
        feat, ew, nidx, seg, out, N, E);
}

// Round 6
// 165.910 us; speedup vs baseline: 2.2729x; 2.2729x over previous
//
#include <hip/hip_runtime.h>

// WeightedAggregator: out[n,:] = sum_{e in seg(n)} eff_w[e]*feat[nidx[e],:] / den[n]
//   wsum[n] = sum of edge_weights in segment n (segment_ids sorted)
//   use_mean = (wsum == 0) -> eff_w = 1, den = deg; else eff_w = w, den = wsum
//   den == 0 -> 1 (empty nodes output zeros)
//
// One wave per node. Latency-bound baseline (9% HBM BW, VALU 28%) -> attack
// the two dependent-load chains:
//  - segment range: 64-ary wave-parallel search (3 ballot rounds) + ballot
//    linear scan for end (~5 loads vs ~42 dependent binary-search probes)
//  - gather: 4 row-slots x 16 lanes, float4 per lane, 2 groups per iter
//    -> 8 independent global_load_dwordx4 in flight per wave.

#define D_FEAT 64

__global__ __launch_bounds__(256) void WeightedAggregator_28424093564968_kernel(
        const float* __restrict__ feat,   // [N, 64]
        const float* __restrict__ ew,     // [E]
        const int*   __restrict__ nidx,   // [E]
        const int*   __restrict__ seg,    // [E] sorted
        float*       __restrict__ out,    // [N, 64]
        int N, int E) {
    const int wave = (blockIdx.x * blockDim.x + threadIdx.x) >> 6;
    const int lane = threadIdx.x & 63;
    if (wave >= N) return;
    const int n = wave;

    // ---- start = lower_bound(seg, n) via 64-ary wave-parallel search ----
    int lo = 0, hi = E;
    while (hi - lo > 64) {
        const long long span = hi - lo;
        const int p = lo + (int)((span * (lane + 1)) / 65);
        const bool ge = seg[p] >= n;
        const unsigned long long mask = __ballot(ge);
        if (mask == 0ull) {
            lo = lo + (int)((span * 64) / 65);
        } else {
            const int first = __ffsll((long long)mask) - 1;
            const int nhi = lo + (int)((span * (first + 1)) / 65);
            const int nlo = (first == 0) ? lo : lo + (int)((span * first) / 65);
            lo = nlo; hi = nhi;
        }
    }
    {   // final linear step over a <=64 window
        const int p = lo + lane;
        const bool ge = (p >= hi) || (seg[p] >= n);
        const unsigned long long mask = __ballot(ge);
        // mask==0 can occur when hi-lo==64 and all window elems < n:
        // the lower bound is then exactly hi.
        lo = (mask == 0ull) ? hi : lo + __ffsll((long long)mask) - 1;
    }
    const int start = lo;

    // ---- end: ballot linear scan (seg[p] > n terminates) ----
    int end = start;
    for (;;) {
        const int p = end + lane;
        const bool stop = (p >= E) || (seg[p] > n);
        const unsigned long long mask = __ballot(stop);
        if (mask) { end += __ffsll((long long)mask) - 1; break; }
        end += 64;
    }

    // ---- per-segment weight sum ----
    float ws = 0.0f;
    for (int e = start + lane; e < end; e += 64) ws += ew[e];
    #pragma unroll
    for (int off = 32; off > 0; off >>= 1) ws += __shfl_xor(ws, off);

    const bool  use_mean = (ws == 0.0f);
    const float deg = (float)(end - start);
    float den = use_mean ? deg : ws;
    if (den == 0.0f) den = 1.0f;

    // ---- weighted gather: 4 slots x float4, 2 groups/iter = 8 loads in flight
    const int slot = lane >> 4;          // 0..3: which edge in the group
    const int dofs = (lane & 15) << 2;   // feature dims [dofs, dofs+4)

    float ax = 0.f, ay = 0.f, az = 0.f, aw = 0.f;
    for (int e = start; e < end; e += 8) {
        const int p0 = e + slot;
        const int p1 = e + 4 + slot;
        const bool v0 = p0 < end;
        const bool v1 = p1 < end;
        const int  i0 = v0 ? nidx[p0] : 0;
        const int  i1 = v1 ? nidx[p1] : 0;
        const float w0 = v0 ? (use_mean ? 1.0f : ew[p0]) : 0.0f;
        const float w1 = v1 ? (use_mean ? 1.0f : ew[p1]) : 0.0f;
        const float4 f0 = *(const float4*)(feat + (size_t)i0 * D_FEAT + dofs);
        const float4 f1 = *(const float4*)(feat + (size_t)i1 * D_FEAT + dofs);
        ax += w0 * f0.x; ay += w0 * f0.y; az += w0 * f0.z; aw += w0 * f0.w;
        ax += w1 * f1.x; ay += w1 * f1.y; az += w1 * f1.z; aw += w1 * f1.w;
    }

    // reduce across the 4 slots (lanes differing in bits 4 and 5)
    #pragma unroll
    for (int m = 16; m <= 32; m <<= 1) {
        ax += __shfl_xor(ax, m);
        ay += __shfl_xor(ay, m);
        az += __shfl_xor(az, m);
        aw += __shfl_xor(aw, m);
    }

    if (slot == 0) {  // lanes 0..15 store a float4 each: 256B coalesced
        const float inv = 1.0f / den;
        float4 r;
        r.x = ax * inv; r.y = ay * inv; r.z = az * inv; r.w = aw * inv;
        *(float4*)(out + (size_t)n * D_FEAT + dofs) = r;
    }
}

extern "C" void kernel_launch(void* const* d_in, const int* in_sizes, int n_in,
                              void* d_out, int out_size, void* d_ws, size_t ws_size,
                              hipStream_t stream) {
    const float* feat = (const float*)d_in[0];
    const float* ew   = (const float*)d_in[1];
    const int*   nidx = (const int*)d_in[2];
    const int*   seg  = (const int*)d_in[3];
    float*       out  = (float*)d_out;

    const int E = in_sizes[1];
    const int N = in_sizes[0] / D_FEAT;

    const int waves_per_block = 256 / 64;
    const int grid = (N + waves_per_block - 1) / waves_per_block;
    WeightedAggregator_28424093564968_kernel<<<grid, 256, 0, stream>>>(
        feat, ew, nidx, seg, out, N, E);
}

// Round 8
// 142.785 us; speedup vs baseline: 2.6410x; 1.1620x over previous
//
#include <hip/hip_runtime.h>

// WeightedAggregator: out[n,:] = sum_{e in seg(n)} eff_w[e]*feat[nidx[e],:] / den[n]
//   wsum[n] = sum of edge_weights in segment n (segment_ids sorted)
//   use_mean = (wsum == 0) -> eff_w = 1, den = deg; else eff_w = w, den = wsum
//   den == 0 -> 1 (empty nodes output zeros)
//
// R6 post-mortem: 95us, BW 2.4 TB/s (30%), VALU 33% -> still latency-bound.
// R7: (a) O(E) offsets pre-pass (boundary scatter into d_ws) removes the
//     per-wave segment search; (b) deg<=64 fast path loads all edge idx/w
//     in ONE coalesced load, then issues all feature gathers back-to-back
//     (idx via __shfl, no load->load dependency inside the loop).

#define D_FEAT 64

// ---- Pass 1: offs[v] = lower_bound(seg, v), v in [0, N] -------------------
__global__ __launch_bounds__(256) void WA_build_offsets_kernel(
        const int* __restrict__ seg, int* __restrict__ offs, int N, int E) {
    const int tid = blockIdx.x * blockDim.x + threadIdx.x;
    if (tid > E) return;
    const int cur  = (tid == E) ? N : seg[tid];
    const int prev = (tid == 0) ? -1 : seg[tid - 1];
    // Only boundary threads loop; avg trip = N/E + 1 ~ 1.06.
    for (int v = prev + 1; v <= cur; ++v) offs[v] = tid;
}

// ---- Pass 2: one wave per node, burst gathers -----------------------------
__global__ __launch_bounds__(256) void WeightedAggregator_28424093564968_kernel(
        const float* __restrict__ feat,   // [N, 64]
        const float* __restrict__ ew,     // [E]
        const int*   __restrict__ nidx,   // [E]
        const int*   __restrict__ offs,   // [N+1]
        float*       __restrict__ out,    // [N, 64]
        int N) {
    const int wave = (blockIdx.x * blockDim.x + threadIdx.x) >> 6;
    const int lane = threadIdx.x & 63;
    if (wave >= N) return;
    const int n = wave;

    // Two independent broadcast loads (no search).
    const int start = offs[n];
    const int end   = offs[n + 1];
    const int deg   = end - start;

    const int slot = lane >> 4;          // 0..3: which edge within a group
    const int dofs = (lane & 15) << 2;   // feature dims [dofs, dofs+4)

    float ax = 0.f, ay = 0.f, az = 0.f, aw = 0.f;
    float den;
    bool  use_mean;

    if (deg <= 64) {
        // One coalesced load grabs the whole segment's idx+w into registers.
        const int  e    = start + lane;
        const bool vl   = lane < deg;
        const int  idxl = vl ? nidx[e] : 0;
        const float wl  = vl ? ew[e]   : 0.0f;

        float ws = wl;
        #pragma unroll
        for (int off = 32; off > 0; off >>= 1) ws += __shfl_xor(ws, off);
        use_mean = (ws == 0.0f);
        den = use_mean ? (float)deg : ws;
        if (den == 0.0f) den = 1.0f;

        // Burst: all gathers independent; idx comes from registers via shfl.
        const int ng = (deg + 3) >> 2;   // groups of 4 edges
        #pragma unroll 4
        for (int g = 0; g < ng; ++g) {
            const int  src = (g << 2) + slot;      // <= 63 always
            const int  ie  = __shfl(idxl, src);    // 0 for padded slots
            float      we  = __shfl(wl, src);
            const bool ve  = src < deg;
            we = ve ? (use_mean ? 1.0f : we) : 0.0f;
            const float4 f = *(const float4*)(feat + (size_t)ie * D_FEAT + dofs);
            ax += we * f.x; ay += we * f.y; az += we * f.z; aw += we * f.w;
        }
    } else {
        // Rare (Poisson(16): deg>64 ~ never) generic path.
        float ws = 0.0f;
        for (int e = start + lane; e < end; e += 64) ws += ew[e];
        #pragma unroll
        for (int off = 32; off > 0; off >>= 1) ws += __shfl_xor(ws, off);
        use_mean = (ws == 0.0f);
        den = use_mean ? (float)deg : ws;
        if (den == 0.0f) den = 1.0f;

        for (int e = start; e < end; e += 8) {
            const int p0 = e + slot;
            const int p1 = e + 4 + slot;
            const bool v0 = p0 < end;
            const bool v1 = p1 < end;
            const int  i0 = v0 ? nidx[p0] : 0;
            const int  i1 = v1 ? nidx[p1] : 0;
            const float w0 = v0 ? (use_mean ? 1.0f : ew[p0]) : 0.0f;
            const float w1 = v1 ? (use_mean ? 1.0f : ew[p1]) : 0.0f;
            const float4 f0 = *(const float4*)(feat + (size_t)i0 * D_FEAT + dofs);
            const float4 f1 = *(const float4*)(feat + (size_t)i1 * D_FEAT + dofs);
            ax += w0 * f0.x; ay += w0 * f0.y; az += w0 * f0.z; aw += w0 * f0.w;
            ax += w1 * f1.x; ay += w1 * f1.y; az += w1 * f1.z; aw += w1 * f1.w;
        }
    }

    // Reduce across the 4 slots (lane bits 4,5).
    #pragma unroll
    for (int m = 16; m <= 32; m <<= 1) {
        ax += __shfl_xor(ax, m);
        ay += __shfl_xor(ay, m);
        az += __shfl_xor(az, m);
        aw += __shfl_xor(aw, m);
    }

    if (slot == 0) {  // lanes 0..15 store a float4 each: 256B coalesced
        const float inv = 1.0f / den;
        float4 r;
        r.x = ax * inv; r.y = ay * inv; r.z = az * inv; r.w = aw * inv;
        *(float4*)(out + (size_t)n * D_FEAT + dofs) = r;
    }
}

// ---- Fallback (ws too small): R6's search-based kernel --------------------
__global__ __launch_bounds__(256) void WA_search_kernel(
        const float* __restrict__ feat, const float* __restrict__ ew,
        const int* __restrict__ nidx, const int* __restrict__ seg,
        float* __restrict__ out, int N, int E) {
    const int wave = (blockIdx.x * blockDim.x + threadIdx.x) >> 6;
    const int lane = threadIdx.x & 63;
    if (wave >= N) return;
    const int n = wave;

    int lo = 0, hi = E;
    while (hi - lo > 64) {
        const long long span = hi - lo;
        const int p = lo + (int)((span * (lane + 1)) / 65);
        const bool ge = seg[p] >= n;
        const unsigned long long mask = __ballot(ge);
        if (mask == 0ull) {
            lo = lo + (int)((span * 64) / 65);
        } else {
            const int first = __ffsll((long long)mask) - 1;
            const int nhi = lo + (int)((span * (first + 1)) / 65);
            const int nlo = (first == 0) ? lo : lo + (int)((span * first) / 65);
            lo = nlo; hi = nhi;
        }
    }
    {
        const int p = lo + lane;
        const bool ge = (p >= hi) || (seg[p] >= n);
        const unsigned long long mask = __ballot(ge);
        lo = (mask == 0ull) ? hi : lo + __ffsll((long long)mask) - 1;
    }
    const int start = lo;
    int end = start;
    for (;;) {
        const int p = end + lane;
        const bool stop = (p >= E) || (seg[p] > n);
        const unsigned long long mask = __ballot(stop);
        if (mask) { end += __ffsll((long long)mask) - 1; break; }
        end += 64;
    }

    float ws = 0.0f;
    for (int e = start + lane; e < end; e += 64) ws += ew[e];
    #pragma unroll
    for (int off = 32; off > 0; off >>= 1) ws += __shfl_xor(ws, off);
    const bool use_mean = (ws == 0.0f);
    float den = use_mean ? (float)(end - start) : ws;
    if (den == 0.0f) den = 1.0f;

    const int slot = lane >> 4;
    const int dofs = (lane & 15) << 2;
    float ax = 0.f, ay = 0.f, az = 0.f, aw = 0.f;
    for (int e = start; e < end; e += 8) {
        const int p0 = e + slot, p1 = e + 4 + slot;
        const bool v0 = p0 < end, v1 = p1 < end;
        const int  i0 = v0 ? nidx[p0] : 0;
        const int  i1 = v1 ? nidx[p1] : 0;
        const float w0 = v0 ? (use_mean ? 1.0f : ew[p0]) : 0.0f;
        const float w1 = v1 ? (use_mean ? 1.0f : ew[p1]) : 0.0f;
        const float4 f0 = *(const float4*)(feat + (size_t)i0 * D_FEAT + dofs);
        const float4 f1 = *(const float4*)(feat + (size_t)i1 * D_FEAT + dofs);
        ax += w0 * f0.x; ay += w0 * f0.y; az += w0 * f0.z; aw += w0 * f0.w;
        ax += w1 * f1.x; ay += w1 * f1.y; az += w1 * f1.z; aw += w1 * f1.w;
    }
    #pragma unroll
    for (int m = 16; m <= 32; m <<= 1) {
        ax += __shfl_xor(ax, m); ay += __shfl_xor(ay, m);
        az += __shfl_xor(az, m); aw += __shfl_xor(aw, m);
    }
    if (slot == 0) {
        const float inv = 1.0f / den;
        float4 r; r.x = ax*inv; r.y = ay*inv; r.z = az*inv; r.w = aw*inv;
        *(float4*)(out + (size_t)n * D_FEAT + dofs) = r;
    }
}

extern "C" void kernel_launch(void* const* d_in, const int* in_sizes, int n_in,
                              void* d_out, int out_size, void* d_ws, size_t ws_size,
                              hipStream_t stream) {
    const float* feat = (const float*)d_in[0];
    const float* ew   = (const float*)d_in[1];
    const int*   nidx = (const int*)d_in[2];
    const int*   seg  = (const int*)d_in[3];
    float*       out  = (float*)d_out;

    const int E = in_sizes[1];
    const int N = in_sizes[0] / D_FEAT;

    const int waves_per_block = 256 / 64;
    const int grid = (N + waves_per_block - 1) / waves_per_block;

    if (ws_size >= (size_t)(N + 1) * sizeof(int)) {
        int* offs = (int*)d_ws;
        const int g1 = (E + 1 + 255) / 256;
        WA_build_offsets_kernel<<<g1, 256, 0, stream>>>(seg, offs, N, E);
        WeightedAggregator_28424093564968_kernel<<<grid, 256, 0, stream>>>(
            feat, ew, nidx, offs, out, N);
    } else {
        WA_search_kernel<<<grid, 256, 0, stream>>>(feat, ew, nidx, seg, out, N, E);
    }
}